// Round 7
// baseline (712.803 us; speedup 1.0000x reference)
//
#include <hip/hip_runtime.h>
#include <math.h>

// Problem constants: N=50000, IN=128, H=4, C=64, HC=256
#define HH 4
#define CC 64
#define HC 256

static constexpr float NEG_SLOPE = 0.2f;
static constexpr float LN_EPS = 1e-5f;

typedef __attribute__((ext_vector_type(8))) short short8;
typedef __attribute__((ext_vector_type(4))) float floatx4;
typedef __attribute__((ext_vector_type(4))) unsigned int uintx4;

__device__ __forceinline__ float bf2f(unsigned short u) {
  return __uint_as_float(((unsigned int)u) << 16);
}
__device__ __forceinline__ unsigned short f2bf(float f) {
  unsigned int u = __float_as_uint(f);
  u = (u + 0x7fff + ((u >> 16) & 1)) >> 16;  // round-to-nearest-even
  return (unsigned short)u;
}
__device__ __forceinline__ unsigned int pack2bf(float a, float b) {
  return (unsigned int)f2bf(a) | ((unsigned int)f2bf(b) << 16);
}
__device__ __forceinline__ void store_out(float* p, float v) { *p = v; }
__device__ __forceinline__ void store_out(unsigned short* p, float v) { *p = f2bf(v); }

// 8 bf16 (as uintx4) * w -> acc[8]
__device__ __forceinline__ void macc8(float* acc, uintx4 h, float w) {
  acc[0] += w * __uint_as_float(h.x << 16);
  acc[1] += w * __uint_as_float(h.x & 0xffff0000u);
  acc[2] += w * __uint_as_float(h.y << 16);
  acc[3] += w * __uint_as_float(h.y & 0xffff0000u);
  acc[4] += w * __uint_as_float(h.z << 16);
  acc[5] += w * __uint_as_float(h.z & 0xffff0000u);
  acc[6] += w * __uint_as_float(h.w << 16);
  acc[7] += w * __uint_as_float(h.w & 0xffff0000u);
}

// ---------------- dtype prep ----------------
__global__ __launch_bounds__(256) void cvt_bf16_x4(
    const float* __restrict__ src, unsigned short* __restrict__ dst, int n4) {
  const int i = blockIdx.x * 256 + threadIdx.x;
  if (i < n4) {
    const float4 v = ((const float4*)src)[i];
    ushort4 o;
    o.x = f2bf(v.x); o.y = f2bf(v.y); o.z = f2bf(v.z); o.w = f2bf(v.w);
    ((ushort4*)dst)[i] = o;
  }
}

// all three weight transposes in one kernel
__global__ __launch_bounds__(256) void cvt_weights(
    const float* __restrict__ W1, const float* __restrict__ W2,
    const float* __restrict__ Wres,
    unsigned short* __restrict__ wt1, unsigned short* __restrict__ wt2,
    unsigned short* __restrict__ wtres) {
  const int idx = blockIdx.x * 256 + threadIdx.x;
  if (idx < 32768) {                       // W1 [128,256]
    const int k = idx >> 8, n = idx & 255;
    wt1[n * 128 + k] = f2bf(W1[idx]);
  } else if (idx < 98304) {                // W2 [256,256]
    const int i = idx - 32768;
    const int k = i >> 8, n = i & 255;
    wt2[n * 256 + k] = f2bf(W2[i]);
  } else if (idx < 106496) {               // Wres [128,64]
    const int i = idx - 98304;
    const int k = i >> 6, n = i & 63;
    wtres[n * 128 + k] = f2bf(Wres[i]);
  }
}

// ---------------- bf16 MFMA GEMM + optional fused alpha epilogue ----------------
template <typename OutT, bool DO_ALPHA>
__global__ __launch_bounds__(256) void gemm_bf16(
    const unsigned short* __restrict__ A, const unsigned short* __restrict__ BT,
    const float* __restrict__ bias, OutT* __restrict__ C,
    const float* __restrict__ att_src, const float* __restrict__ att_dst,
    float* __restrict__ as_, float* __restrict__ ad_,
    int M, int Nc, int K) {
  __shared__ unsigned short As[64][40];
  __shared__ unsigned short Bs[64][40];
  const int tid = threadIdx.x;
  const int w = tid >> 6;
  const int lane = tid & 63;
  const int q = lane >> 4;
  const int mr = lane & 15;
  const int row0 = blockIdx.x * 64;
  const int col0 = blockIdx.y * 64;
  const int sr = tid >> 2;
  const int sk = (tid & 3) * 8;

  floatx4 acc[4] = {};

  for (int k0 = 0; k0 < K; k0 += 32) {
    const int arow = row0 + sr;
    short8 av8 = {};
    if (arow < M) av8 = *(const short8*)(A + (size_t)arow * K + k0 + sk);
    *(short8*)(&As[sr][sk]) = av8;
    *(short8*)(&Bs[sr][sk]) = *(const short8*)(BT + (size_t)(col0 + sr) * K + k0 + sk);
    __syncthreads();
    const short8 af = *(const short8*)(&As[w * 16 + mr][q * 8]);
#pragma unroll
    for (int ct = 0; ct < 4; ++ct) {
      const short8 bf = *(const short8*)(&Bs[ct * 16 + mr][q * 8]);
      acc[ct] = __builtin_amdgcn_mfma_f32_16x16x32_bf16(af, bf, acc[ct], 0, 0, 0);
    }
    __syncthreads();
  }
#pragma unroll
  for (int ct = 0; ct < 4; ++ct) {
#pragma unroll
    for (int r = 0; r < 4; ++r) {
      const int row = row0 + w * 16 + q * 4 + r;
      if (row < M) {
        const int cc = col0 + ct * 16 + mr;
        float v = acc[ct][r];
        if (bias) v += bias[cc];
        store_out(C + (size_t)row * Nc + cc, v);
      }
    }
  }
  if (DO_ALPHA) {
    const int hh = col0 >> 6;
    float pa[4] = {}, pb[4] = {};
#pragma unroll
    for (int ct = 0; ct < 4; ++ct) {
      const float a_s = att_src[col0 + ct * 16 + mr];
      const float a_d = att_dst[col0 + ct * 16 + mr];
#pragma unroll
      for (int r = 0; r < 4; ++r) {
        pa[r] += acc[ct][r] * a_s;
        pb[r] += acc[ct][r] * a_d;
      }
    }
#pragma unroll
    for (int off = 1; off < 16; off <<= 1) {
#pragma unroll
      for (int r = 0; r < 4; ++r) {
        pa[r] += __shfl_xor(pa[r], off);
        pb[r] += __shfl_xor(pb[r], off);
      }
    }
    if (mr == 0) {
#pragma unroll
      for (int r = 0; r < 4; ++r) {
        const int row = row0 + w * 16 + q * 4 + r;
        if (row < M) {
          as_[row * 4 + hh] = pa[r];
          ad_[row * 4 + hh] = pb[r];
        }
      }
    }
  }
}

// ================= CSR construction =================
__global__ __launch_bounds__(256) void deg_hist(
    const int* __restrict__ dsts, int* __restrict__ deg, int E) {
  const int e = blockIdx.x * 256 + threadIdx.x;
  if (e < E) atomicAdd(&deg[dsts[e]], 1);
}

__global__ __launch_bounds__(256) void scan_block(
    const int* __restrict__ deg, int* __restrict__ rowptr, int* __restrict__ bsum, int N) {
  const int b = blockIdx.x, t = threadIdx.x, g = b * 256 + t;
  const int lane = t & 63, w = t >> 6;
  int x = (g < N) ? deg[g] + 1 : 0;
#pragma unroll
  for (int off = 1; off < 64; off <<= 1) {
    const int y = __shfl_up(x, off);
    if (lane >= off) x += y;
  }
  __shared__ int wsum[4];
  if (lane == 63) wsum[w] = x;
  __syncthreads();
  int add = 0;
  for (int i = 0; i < w; ++i) add += wsum[i];
  x += add;
  if (g < N) rowptr[g + 1] = x;
  if (t == 255) bsum[b] = x;
}

__global__ __launch_bounds__(256) void scan_top(int* __restrict__ bsum, int nb) {
  const int t = threadIdx.x;
  const int lane = t & 63, w = t >> 6;
  const int v = (t < nb) ? bsum[t] : 0;
  int x = v;
#pragma unroll
  for (int off = 1; off < 64; off <<= 1) {
    const int y = __shfl_up(x, off);
    if (lane >= off) x += y;
  }
  __shared__ int wsum[4];
  if (lane == 63) wsum[w] = x;
  __syncthreads();
  int add = 0;
  for (int i = 0; i < w; ++i) add += wsum[i];
  x += add;
  if (t < nb) bsum[t] = x - v;  // exclusive
}

__global__ __launch_bounds__(256) void scan_add(
    const int* __restrict__ bsum, int* __restrict__ rowptr,
    int* __restrict__ deg_to_cursor, int N) {
  const int g = blockIdx.x * 256 + threadIdx.x;
  if (g == 0) rowptr[0] = 0;
  if (g < N) {
    const int v = rowptr[g + 1] + bsum[blockIdx.x];
    rowptr[g + 1] = v;
    deg_to_cursor[g] = v - deg_to_cursor[g] - 1;
  }
}

__global__ __launch_bounds__(256) void csr_scatter(
    const int* __restrict__ srcs, const int* __restrict__ dsts,
    int* __restrict__ cursor, int* __restrict__ col, int E, int N) {
  const int e = blockIdx.x * 256 + threadIdx.x;
  if (e >= E + N) return;
  int s, d;
  if (e < E) { s = srcs[e]; d = dsts[e]; }
  else       { s = e - E; d = s; }
  const int pos = atomicAdd(&cursor[d], 1);
  col[pos] = s;
}

// ================= XCD-sliced CSR aggregation =================
// slice = blockIdx % 8 -> (head = slice>>1, channel-half = slice&1): with
// round-robin block->XCD dispatch, each XCD touches only a 3.2 MB table slice
// (fits 4 MB L2). Wave w of each block aggregates node (blockIdx/8)*4+w.
// Lane = 16 edge-subgroups x 4 channel-groups; 16 edges per dwordx4 gather.
__global__ __launch_bounds__(256) void csr_agg_sliced(
    const int* __restrict__ rowptr, const int* __restrict__ col,
    const float* __restrict__ as_, const float* __restrict__ ad_,
    const unsigned short* __restrict__ hlin, unsigned short* __restrict__ agg,
    int N) {
  const int slice = blockIdx.x & 7;
  const int hh = slice >> 1, chalf = slice & 1;
  const int w = threadIdx.x >> 6, lane = threadIdx.x & 63;
  const int n = (blockIdx.x >> 3) * 4 + w;
  if (n >= N) return;
  const int sub = lane >> 2, cg = lane & 3;
  const uintx4* hb = (const uintx4*)hlin;         // 32 uintx4 per node row
  const int hoff = hh * 8 + chalf * 4 + cg;       // uintx4 offset within row
  const float adv = ad_[n * 4 + hh];
  const int beg = rowptr[n], end = rowptr[n + 1];
  float acc[8] = {};
  float wsum = 0.f;
  for (int off = beg; off < end; off += 64) {
    const int len = min(64, end - off);
    int s_l = 0;
    float w_l = 0.f;
    if (lane < len) {
      s_l = __builtin_nontemporal_load(&col[off + lane]);
      float v = as_[s_l * 4 + hh] + adv;
      v = v > 0.f ? v : NEG_SLOPE * v;
      w_l = expf(v);
    }
    wsum += w_l;
    for (int j = 0; j < len; j += 16) {
      const int s = __shfl(s_l, j + sub);        // w=0 for padded lanes
      const float wt = __shfl(w_l, j + sub);
      macc8(acc, hb[(size_t)s * 32 + hoff], wt);
    }
  }
#pragma unroll
  for (int o = 32; o > 0; o >>= 1) wsum += __shfl_xor(wsum, o);
#pragma unroll
  for (int t = 0; t < 8; ++t) {
    acc[t] += __shfl_xor(acc[t], 4);
    acc[t] += __shfl_xor(acc[t], 8);
    acc[t] += __shfl_xor(acc[t], 16);
    acc[t] += __shfl_xor(acc[t], 32);
  }
  if (sub == 0) {
    const float inv = 1.0f / wsum;
    uintx4 o;
    o.x = pack2bf(acc[0] * inv, acc[1] * inv);
    o.y = pack2bf(acc[2] * inv, acc[3] * inv);
    o.z = pack2bf(acc[4] * inv, acc[5] * inv);
    o.w = pack2bf(acc[6] * inv, acc[7] * inv);
    __builtin_nontemporal_store(o, (uintx4*)agg + (size_t)n * 32 + hoff);
  }
}

// ---------------- +bias1, LN(256), ELU : agg bf16 -> h1 bf16 ----------------
__global__ __launch_bounds__(256) void ln_elu1(
    const unsigned short* __restrict__ agg, const float* __restrict__ bias1,
    const float* __restrict__ g1, const float* __restrict__ b1,
    unsigned short* __restrict__ h1) {
  const int n = blockIdx.x;
  const int tid = threadIdx.x;
  const int hh = tid >> 6, lane = tid & 63;
  const float val = bf2f(agg[(size_t)n * HC + tid]) + bias1[tid];
  float s1 = val, s2 = val * val;
#pragma unroll
  for (int off = 32; off > 0; off >>= 1) {
    s1 += __shfl_down(s1, off);
    s2 += __shfl_down(s2, off);
  }
  __shared__ float ws1[4], ws2[4];
  if (lane == 0) { ws1[hh] = s1; ws2[hh] = s2; }
  __syncthreads();
  const float tot1 = ws1[0] + ws1[1] + ws1[2] + ws1[3];
  const float tot2 = ws2[0] + ws2[1] + ws2[2] + ws2[3];
  const float mu = tot1 * (1.0f / HC);
  const float var = tot2 * (1.0f / HC) - mu * mu;
  float y = (val - mu) * rsqrtf(var + LN_EPS) * g1[tid] + b1[tid];
  y = y > 0.f ? y : expm1f(y);
  h1[(size_t)n * HC + tid] = f2bf(y);
}

// ---------------- head-mean + bias2 + LN(64) + residual + ELU -> out ----------------
__global__ __launch_bounds__(64) void final_kernel(
    const unsigned short* __restrict__ agg2, const float* __restrict__ ident,
    const float* __restrict__ bias2, const float* __restrict__ g2,
    const float* __restrict__ b2, float* __restrict__ out) {
  const int n = blockIdx.x;
  const int c = threadIdx.x;
  const size_t base = (size_t)n * HC;
  float v = 0.25f * (bf2f(agg2[base + c]) + bf2f(agg2[base + 64 + c]) +
                     bf2f(agg2[base + 128 + c]) + bf2f(agg2[base + 192 + c])) +
            bias2[c];
  float s1 = v, s2 = v * v;
#pragma unroll
  for (int off = 32; off > 0; off >>= 1) {
    s1 += __shfl_down(s1, off);
    s2 += __shfl_down(s2, off);
  }
  s1 = __shfl(s1, 0);
  s2 = __shfl(s2, 0);
  const float mu = s1 * (1.0f / 64.0f);
  const float var = s2 * (1.0f / 64.0f) - mu * mu;
  float y = (v - mu) * rsqrtf(var + LN_EPS) * g2[c] + b2[c];
  y += ident[(size_t)n * 64 + c];
  out[(size_t)n * 64 + c] = y > 0.f ? y : expm1f(y);
}

extern "C" void kernel_launch(void* const* d_in, const int* in_sizes, int n_in,
                              void* d_out, int out_size, void* d_ws, size_t ws_size,
                              hipStream_t stream) {
  const float* x        = (const float*)d_in[0];
  const int*   ei       = (const int*)d_in[1];
  const float* W1       = (const float*)d_in[2];
  const float* att_src1 = (const float*)d_in[3];
  const float* att_dst1 = (const float*)d_in[4];
  const float* bias1    = (const float*)d_in[5];
  const float* g1       = (const float*)d_in[6];
  const float* b1       = (const float*)d_in[7];
  const float* W2       = (const float*)d_in[8];
  const float* att_src2 = (const float*)d_in[9];
  const float* att_dst2 = (const float*)d_in[10];
  const float* bias2    = (const float*)d_in[11];
  const float* g2       = (const float*)d_in[12];
  const float* b2       = (const float*)d_in[13];
  const float* Wres     = (const float*)d_in[14];
  const float* bres     = (const float*)d_in[15];

  const int N = in_sizes[0] / 128;   // 50000
  const int E = in_sizes[1] / 2;     // 800000
  const int IN = 128;
  const int Etot = E + N;

  const int* srcs = ei;
  const int* dsts = ei + E;

  // workspace layout
  char* p = (char*)d_ws;
  float* ident = (float*)p;            p += (size_t)N * 64 * 4;
  float* as_   = (float*)p;            p += (size_t)N * HH * 4;
  float* ad_   = (float*)p;            p += (size_t)N * HH * 4;
  int* rowptr  = (int*)p;              p += (size_t)(N + 4) * 4;
  int* deg     = (int*)p;              p += (size_t)N * 4;
  int* bsum    = (int*)p;              p += 256 * 4;
  int* col     = (int*)p;              p += (size_t)Etot * 4;
  p = (char*)(((uintptr_t)p + 15) & ~(uintptr_t)15);
  unsigned short* xb    = (unsigned short*)p; p += (size_t)N * IN * 2;
  unsigned short* hlinb = (unsigned short*)p; p += (size_t)N * HC * 2;
  unsigned short* h1b   = (unsigned short*)p; p += (size_t)N * HC * 2;
  unsigned short* aggb  = (unsigned short*)p; p += (size_t)N * HC * 2;
  unsigned short* wt1   = (unsigned short*)p; p += (size_t)IN * HC * 2;
  unsigned short* wt2   = (unsigned short*)p; p += (size_t)HC * HC * 2;
  unsigned short* wtres = (unsigned short*)p; p += (size_t)IN * 64 * 2;

  const int mblocks = (N + 63) / 64;
  const int nscan = (N + 255) / 256;
  const int aggblocks = ((N + 3) / 4) * 8;
  dim3 blk(256);

  // ---- dtype prep ----
  cvt_bf16_x4<<<(N * IN / 4 + 255) / 256, blk, 0, stream>>>(x, xb, N * IN / 4);
  cvt_weights<<<(106496 + 255) / 256, blk, 0, stream>>>(W1, W2, Wres, wt1, wt2, wtres);

  // ---- CSR build ----
  (void)hipMemsetAsync(deg, 0, (size_t)N * sizeof(int), stream);
  deg_hist<<<(E + 255) / 256, blk, 0, stream>>>(dsts, deg, E);
  scan_block<<<nscan, blk, 0, stream>>>(deg, rowptr, bsum, N);
  scan_top<<<1, blk, 0, stream>>>(bsum, nscan);
  scan_add<<<nscan, blk, 0, stream>>>(bsum, rowptr, deg, N);
  csr_scatter<<<(Etot + 255) / 256, blk, 0, stream>>>(srcs, dsts, deg, col, E, N);

  // residual projection
  gemm_bf16<float, false><<<dim3(mblocks, 1), blk, 0, stream>>>(
      xb, wtres, bres, ident, nullptr, nullptr, nullptr, nullptr, N, 64, IN);

  // ---- GAT layer 1 ----
  gemm_bf16<unsigned short, true><<<dim3(mblocks, 4), blk, 0, stream>>>(
      xb, wt1, nullptr, hlinb, att_src1, att_dst1, as_, ad_, N, HC, IN);
  csr_agg_sliced<<<aggblocks, blk, 0, stream>>>(rowptr, col, as_, ad_, hlinb, aggb, N);
  ln_elu1<<<N, blk, 0, stream>>>(aggb, bias1, g1, b1, h1b);

  // ---- GAT layer 2 ----
  gemm_bf16<unsigned short, true><<<dim3(mblocks, 4), blk, 0, stream>>>(
      h1b, wt2, nullptr, hlinb, att_src2, att_dst2, as_, ad_, N, HC, HC);
  csr_agg_sliced<<<aggblocks, blk, 0, stream>>>(rowptr, col, as_, ad_, hlinb, aggb, N);
  final_kernel<<<N, dim3(64), 0, stream>>>(aggb, ident, bias2, g2, b2, (float*)d_out);
}

// Round 10
// 480.469 us; speedup vs baseline: 1.4836x; 1.4836x over previous
//
#include <hip/hip_runtime.h>
#include <math.h>

// Problem constants: N=50000, IN=128, H=4, C=64, HC=256
#define HH 4
#define CC 64
#define HC 256

static constexpr float NEG_SLOPE = 0.2f;
static constexpr float LN_EPS = 1e-5f;

typedef __attribute__((ext_vector_type(8))) short short8;
typedef __attribute__((ext_vector_type(4))) float floatx4;
typedef __attribute__((ext_vector_type(4))) unsigned int uintx4;

__device__ __forceinline__ float bf2f(unsigned short u) {
  return __uint_as_float(((unsigned int)u) << 16);
}
__device__ __forceinline__ unsigned short f2bf(float f) {
  unsigned int u = __float_as_uint(f);
  u = (u + 0x7fff + ((u >> 16) & 1)) >> 16;  // round-to-nearest-even
  return (unsigned short)u;
}
__device__ __forceinline__ void store_out(float* p, float v) { *p = v; }
__device__ __forceinline__ void store_out(unsigned short* p, float v) { *p = f2bf(v); }

// 8 bf16 (as uintx4) * w -> acc[8]; 2 VALU per element
__device__ __forceinline__ void macc8(float* acc, uintx4 h, float w) {
  acc[0] += w * __uint_as_float(h.x << 16);
  acc[1] += w * __uint_as_float(h.x & 0xffff0000u);
  acc[2] += w * __uint_as_float(h.y << 16);
  acc[3] += w * __uint_as_float(h.y & 0xffff0000u);
  acc[4] += w * __uint_as_float(h.z << 16);
  acc[5] += w * __uint_as_float(h.z & 0xffff0000u);
  acc[6] += w * __uint_as_float(h.w << 16);
  acc[7] += w * __uint_as_float(h.w & 0xffff0000u);
}

// ---------------- dtype prep ----------------
__global__ __launch_bounds__(256) void cvt_bf16_x4(
    const float* __restrict__ src, unsigned short* __restrict__ dst, int n4) {
  const int i = blockIdx.x * 256 + threadIdx.x;
  if (i < n4) {
    const float4 v = ((const float4*)src)[i];
    ushort4 o;
    o.x = f2bf(v.x); o.y = f2bf(v.y); o.z = f2bf(v.z); o.w = f2bf(v.w);
    ((ushort4*)dst)[i] = o;
  }
}

// all three weight transposes in one kernel
__global__ __launch_bounds__(256) void cvt_weights(
    const float* __restrict__ W1, const float* __restrict__ W2,
    const float* __restrict__ Wres,
    unsigned short* __restrict__ wt1, unsigned short* __restrict__ wt2,
    unsigned short* __restrict__ wtres) {
  const int idx = blockIdx.x * 256 + threadIdx.x;
  if (idx < 32768) {                       // W1 [128,256]
    const int k = idx >> 8, n = idx & 255;
    wt1[n * 128 + k] = f2bf(W1[idx]);
  } else if (idx < 98304) {                // W2 [256,256]
    const int i = idx - 32768;
    const int k = i >> 8, n = i & 255;
    wt2[n * 256 + k] = f2bf(W2[i]);
  } else if (idx < 106496) {               // Wres [128,64]
    const int i = idx - 98304;
    const int k = i >> 6, n = i & 63;
    wtres[n * 128 + k] = f2bf(Wres[i]);
  }
}

// ---------------- 64-tile bf16 MFMA GEMM (residual projection only) ----------------
template <typename OutT>
__global__ __launch_bounds__(256) void gemm_bf16(
    const unsigned short* __restrict__ A, const unsigned short* __restrict__ BT,
    const float* __restrict__ bias, OutT* __restrict__ C,
    int M, int Nc, int K) {
  __shared__ unsigned short As[64][40];
  __shared__ unsigned short Bs[64][40];
  const int tid = threadIdx.x;
  const int w = tid >> 6;
  const int lane = tid & 63;
  const int q = lane >> 4;
  const int mr = lane & 15;
  const int row0 = blockIdx.x * 64;
  const int col0 = blockIdx.y * 64;
  const int sr = tid >> 2;
  const int sk = (tid & 3) * 8;

  floatx4 acc[4] = {};

  for (int k0 = 0; k0 < K; k0 += 32) {
    const int arow = row0 + sr;
    short8 av8 = {};
    if (arow < M) av8 = *(const short8*)(A + (size_t)arow * K + k0 + sk);
    *(short8*)(&As[sr][sk]) = av8;
    *(short8*)(&Bs[sr][sk]) = *(const short8*)(BT + (size_t)(col0 + sr) * K + k0 + sk);
    __syncthreads();
    const short8 af = *(const short8*)(&As[w * 16 + mr][q * 8]);
#pragma unroll
    for (int ct = 0; ct < 4; ++ct) {
      const short8 bf = *(const short8*)(&Bs[ct * 16 + mr][q * 8]);
      acc[ct] = __builtin_amdgcn_mfma_f32_16x16x32_bf16(af, bf, acc[ct], 0, 0, 0);
    }
    __syncthreads();
  }
#pragma unroll
  for (int ct = 0; ct < 4; ++ct) {
#pragma unroll
    for (int r = 0; r < 4; ++r) {
      const int row = row0 + w * 16 + q * 4 + r;
      if (row < M) {
        const int cc = col0 + ct * 16 + mr;
        float v = acc[ct][r];
        if (bias) v += bias[cc];
        store_out(C + (size_t)row * Nc + cc, v);
      }
    }
  }
}

// ---------------- 128x128-tile bf16 MFMA GEMM + fused alpha epilogue ----------------
// A [M,K] bf16; BT [Nc,K] bf16. 4 waves in 2x2 quadrants, each wave: 4x4 acc
// tiles of 16x16, 16 MFMA per BK=32 step. Register-prefetch pipeline.
// Each wave's 64-col quadrant = exactly one head -> in-register alpha reduce.
__global__ __launch_bounds__(256) void gemm128(
    const unsigned short* __restrict__ A, const unsigned short* __restrict__ BT,
    unsigned short* __restrict__ C,
    const float* __restrict__ att_src, const float* __restrict__ att_dst,
    float* __restrict__ as_, float* __restrict__ ad_,
    int M, int Nc, int K) {
  __shared__ unsigned short As[128][40];
  __shared__ unsigned short Bs[128][40];
  const int tid = threadIdx.x;
  const int w = tid >> 6, lane = tid & 63;
  const int q = lane >> 4, mr = lane & 15;
  const int rh = w >> 1, ch = w & 1;          // quadrant (row-half, col-half)
  const int row0 = blockIdx.x * 128;
  const int col0 = blockIdx.y * 128;
  const int sr = tid >> 2;                    // 0..63 staging row
  const int sk = (tid & 3) * 8;               // k offset (halves)

  floatx4 acc[4][4] = {};

  // prefetch tile 0 into registers
  short8 a0 = {}, a1 = {}, b0, b1;
  {
    const int r0 = row0 + sr, r1 = row0 + sr + 64;
    if (r0 < M) a0 = *(const short8*)(A + (size_t)r0 * K + sk);
    if (r1 < M) a1 = *(const short8*)(A + (size_t)r1 * K + sk);
    b0 = *(const short8*)(BT + (size_t)(col0 + sr) * K + sk);
    b1 = *(const short8*)(BT + (size_t)(col0 + sr + 64) * K + sk);
  }
  for (int k0 = 0; k0 < K; k0 += 32) {
    *(short8*)(&As[sr][sk]) = a0;
    *(short8*)(&As[sr + 64][sk]) = a1;
    *(short8*)(&Bs[sr][sk]) = b0;
    *(short8*)(&Bs[sr + 64][sk]) = b1;
    __syncthreads();
    const int kn = k0 + 32;
    if (kn < K) {  // prefetch next tile while MFMA runs
      const int r0 = row0 + sr, r1 = row0 + sr + 64;
      a0 = (r0 < M) ? *(const short8*)(A + (size_t)r0 * K + kn + sk) : short8{};
      a1 = (r1 < M) ? *(const short8*)(A + (size_t)r1 * K + kn + sk) : short8{};
      b0 = *(const short8*)(BT + (size_t)(col0 + sr) * K + kn + sk);
      b1 = *(const short8*)(BT + (size_t)(col0 + sr + 64) * K + kn + sk);
    }
    short8 af[4], bf[4];
#pragma unroll
    for (int i = 0; i < 4; ++i)
      af[i] = *(const short8*)(&As[rh * 64 + i * 16 + mr][q * 8]);
#pragma unroll
    for (int j = 0; j < 4; ++j)
      bf[j] = *(const short8*)(&Bs[ch * 64 + j * 16 + mr][q * 8]);
#pragma unroll
    for (int i = 0; i < 4; ++i)
#pragma unroll
      for (int j = 0; j < 4; ++j)
        acc[i][j] = __builtin_amdgcn_mfma_f32_16x16x32_bf16(af[i], bf[j], acc[i][j], 0, 0, 0);
    __syncthreads();
  }
  // C store (bf16). C/D layout: col=mr, row=q*4+rr within each 16x16 tile.
#pragma unroll
  for (int i = 0; i < 4; ++i) {
#pragma unroll
    for (int j = 0; j < 4; ++j) {
#pragma unroll
      for (int rr = 0; rr < 4; ++rr) {
        const int row = row0 + rh * 64 + i * 16 + q * 4 + rr;
        if (row < M) {
          const int cc = col0 + ch * 64 + j * 16 + mr;
          C[(size_t)row * Nc + cc] = f2bf(acc[i][j][rr]);
        }
      }
    }
  }
  // fused alpha: head hh = this wave's 64-col quadrant
  const int hh = (col0 >> 6) + ch;
  float pa[16] = {}, pb[16] = {};
#pragma unroll
  for (int j = 0; j < 4; ++j) {
    const float a_s = att_src[hh * 64 + j * 16 + mr];
    const float a_d = att_dst[hh * 64 + j * 16 + mr];
#pragma unroll
    for (int i = 0; i < 4; ++i)
#pragma unroll
      for (int rr = 0; rr < 4; ++rr) {
        pa[i * 4 + rr] += acc[i][j][rr] * a_s;
        pb[i * 4 + rr] += acc[i][j][rr] * a_d;
      }
  }
#pragma unroll
  for (int off = 1; off < 16; off <<= 1) {
#pragma unroll
    for (int t = 0; t < 16; ++t) {
      pa[t] += __shfl_xor(pa[t], off);
      pb[t] += __shfl_xor(pb[t], off);
    }
  }
  if (mr == 0) {
#pragma unroll
    for (int i = 0; i < 4; ++i)
#pragma unroll
      for (int rr = 0; rr < 4; ++rr) {
        const int row = row0 + rh * 64 + i * 16 + q * 4 + rr;
        if (row < M) {
          as_[row * 4 + hh] = pa[i * 4 + rr];
          ad_[row * 4 + hh] = pb[i * 4 + rr];
        }
      }
  }
}

// ================= CSR construction =================
__global__ __launch_bounds__(256) void deg_hist(
    const int* __restrict__ dsts, int* __restrict__ deg, int E) {
  const int e = blockIdx.x * 256 + threadIdx.x;
  if (e < E) atomicAdd(&deg[dsts[e]], 1);
}

// deg counts edges only; +1 here for the self-loop.
__global__ __launch_bounds__(256) void scan_block(
    const int* __restrict__ deg, int* __restrict__ rowptr, int* __restrict__ bsum, int N) {
  const int b = blockIdx.x, t = threadIdx.x, g = b * 256 + t;
  const int lane = t & 63, w = t >> 6;
  int x = (g < N) ? deg[g] + 1 : 0;
#pragma unroll
  for (int off = 1; off < 64; off <<= 1) {
    const int y = __shfl_up(x, off);
    if (lane >= off) x += y;
  }
  __shared__ int wsum[4];
  if (lane == 63) wsum[w] = x;
  __syncthreads();
  int add = 0;
  for (int i = 0; i < w; ++i) add += wsum[i];
  x += add;
  if (g < N) rowptr[g + 1] = x;
  if (t == 255) bsum[b] = x;
}

__global__ __launch_bounds__(256) void scan_top(int* __restrict__ bsum, int nb) {
  const int t = threadIdx.x;
  const int lane = t & 63, w = t >> 6;
  const int v = (t < nb) ? bsum[t] : 0;
  int x = v;
#pragma unroll
  for (int off = 1; off < 64; off <<= 1) {
    const int y = __shfl_up(x, off);
    if (lane >= off) x += y;
  }
  __shared__ int wsum[4];
  if (lane == 63) wsum[w] = x;
  __syncthreads();
  int add = 0;
  for (int i = 0; i < w; ++i) add += wsum[i];
  x += add;
  if (t < nb) bsum[t] = x - v;  // exclusive
}

__global__ __launch_bounds__(256) void scan_add(
    const int* __restrict__ bsum, int* __restrict__ rowptr,
    int* __restrict__ deg_to_cursor, int N) {
  const int g = blockIdx.x * 256 + threadIdx.x;
  if (g == 0) rowptr[0] = 0;
  if (g < N) {
    const int v = rowptr[g + 1] + bsum[blockIdx.x];
    rowptr[g + 1] = v;
    deg_to_cursor[g] = v - deg_to_cursor[g] - 1;  // exclusive start
  }
}

__global__ __launch_bounds__(256) void csr_scatter(
    const int* __restrict__ srcs, const int* __restrict__ dsts,
    int* __restrict__ cursor, int* __restrict__ col, int E, int N) {
  const int e = blockIdx.x * 256 + threadIdx.x;
  if (e >= E + N) return;
  int s, d;
  if (e < E) { s = srcs[e]; d = dsts[e]; }
  else       { s = e - E; d = s; }
  const int pos = atomicAdd(&cursor[d], 1);
  col[pos] = s;
}

// ================= fused CSR aggregation (bf16, vectorized + 2x unrolled) =================
__global__ __launch_bounds__(256) void csr_agg_ln1(
    const int* __restrict__ rowptr, const int* __restrict__ col,
    const float* __restrict__ as_, const float* __restrict__ ad_,
    const unsigned short* __restrict__ hlin, const float* __restrict__ bias1,
    const float* __restrict__ g1, const float* __restrict__ b1,
    unsigned short* __restrict__ h1) {
  const int n = blockIdx.x;
  const int tid = threadIdx.x;
  const int hh = tid >> 6, lane = tid & 63;
  const int sub = lane >> 3, cg = lane & 7;
  const uintx4* hb = (const uintx4*)(hlin + hh * 64 + cg * 8);  // row stride 32 uintx4
  const float adv = ad_[n * 4 + hh];
  const int beg = rowptr[n], end = rowptr[n + 1];
  float acc[8] = {};
  float wsum = 0.f;
  for (int off = beg; off < end; off += 64) {
    const int len = min(64, end - off);
    int s_l = 0;
    float w_l = 0.f;
    if (lane < len) {
      s_l = col[off + lane];
      float v = as_[s_l * 4 + hh] + adv;
      v = v > 0.f ? v : NEG_SLOPE * v;
      w_l = expf(v);
    }
    wsum += w_l;
    int j = 0;
    for (; j + 16 <= len; j += 16) {
      const int sA = __shfl(s_l, j + sub);
      const int sB = __shfl(s_l, j + 8 + sub);
      const float wA = __shfl(w_l, j + sub);
      const float wB = __shfl(w_l, j + 8 + sub);
      const uintx4 hA = hb[(size_t)sA * 32];
      const uintx4 hB = hb[(size_t)sB * 32];
      macc8(acc, hA, wA);
      macc8(acc, hB, wB);
    }
    for (; j < len; j += 8) {
      const int s = __shfl(s_l, j + sub);
      const float w = __shfl(w_l, j + sub);
      macc8(acc, hb[(size_t)s * 32], w);
    }
  }
#pragma unroll
  for (int off = 32; off > 0; off >>= 1) wsum += __shfl_xor(wsum, off);
#pragma unroll
  for (int t = 0; t < 8; ++t) {
    acc[t] += __shfl_xor(acc[t], 8);
    acc[t] += __shfl_xor(acc[t], 16);
    acc[t] += __shfl_xor(acc[t], 32);
  }
  __shared__ float vals[HC];
  if (sub == 0) {
    const float inv = 1.0f / wsum;
#pragma unroll
    for (int t = 0; t < 8; ++t) vals[hh * 64 + cg * 8 + t] = acc[t] * inv;
  }
  __syncthreads();
  const float val = vals[tid] + bias1[tid];
  float s1 = val, s2 = val * val;
#pragma unroll
  for (int off = 32; off > 0; off >>= 1) {
    s1 += __shfl_down(s1, off);
    s2 += __shfl_down(s2, off);
  }
  __shared__ float ws1[4], ws2[4];
  if (lane == 0) { ws1[hh] = s1; ws2[hh] = s2; }
  __syncthreads();
  const float tot1 = ws1[0] + ws1[1] + ws1[2] + ws1[3];
  const float tot2 = ws2[0] + ws2[1] + ws2[2] + ws2[3];
  const float mu = tot1 * (1.0f / HC);
  const float var = tot2 * (1.0f / HC) - mu * mu;
  float y = (val - mu) * rsqrtf(var + LN_EPS) * g1[tid] + b1[tid];
  y = y > 0.f ? y : expm1f(y);
  h1[(size_t)n * HC + tid] = f2bf(y);
}

__global__ __launch_bounds__(256) void csr_agg_final(
    const int* __restrict__ rowptr, const int* __restrict__ col,
    const float* __restrict__ as_, const float* __restrict__ ad_,
    const unsigned short* __restrict__ hlin, const float* __restrict__ ident,
    const float* __restrict__ bias2, const float* __restrict__ g2,
    const float* __restrict__ b2, float* __restrict__ out) {
  const int n = blockIdx.x;
  const int tid = threadIdx.x;
  const int hh = tid >> 6, lane = tid & 63;
  const int sub = lane >> 3, cg = lane & 7;
  const uintx4* hb = (const uintx4*)(hlin + hh * 64 + cg * 8);
  const float adv = ad_[n * 4 + hh];
  const int beg = rowptr[n], end = rowptr[n + 1];
  float acc[8] = {};
  float wsum = 0.f;
  for (int off = beg; off < end; off += 64) {
    const int len = min(64, end - off);
    int s_l = 0;
    float w_l = 0.f;
    if (lane < len) {
      s_l = col[off + lane];
      float v = as_[s_l * 4 + hh] + adv;
      v = v > 0.f ? v : NEG_SLOPE * v;
      w_l = expf(v);
    }
    wsum += w_l;
    int j = 0;
    for (; j + 16 <= len; j += 16) {
      const int sA = __shfl(s_l, j + sub);
      const int sB = __shfl(s_l, j + 8 + sub);
      const float wA = __shfl(w_l, j + sub);
      const float wB = __shfl(w_l, j + 8 + sub);
      const uintx4 hA = hb[(size_t)sA * 32];
      const uintx4 hB = hb[(size_t)sB * 32];
      macc8(acc, hA, wA);
      macc8(acc, hB, wB);
    }
    for (; j < len; j += 8) {
      const int s = __shfl(s_l, j + sub);
      const float w = __shfl(w_l, j + sub);
      macc8(acc, hb[(size_t)s * 32], w);
    }
  }
#pragma unroll
  for (int off = 32; off > 0; off >>= 1) wsum += __shfl_xor(wsum, off);
#pragma unroll
  for (int t = 0; t < 8; ++t) {
    acc[t] += __shfl_xor(acc[t], 8);
    acc[t] += __shfl_xor(acc[t], 16);
    acc[t] += __shfl_xor(acc[t], 32);
  }
  __shared__ float sm[4][64];
  if (sub == 0) {
    const float inv = 1.0f / wsum;
#pragma unroll
    for (int t = 0; t < 8; ++t) sm[hh][cg * 8 + t] = acc[t] * inv;
  }
  __syncthreads();
  if (tid < 64) {
    float v = 0.25f * (sm[0][tid] + sm[1][tid] + sm[2][tid] + sm[3][tid]) + bias2[tid];
    float s1 = v, s2 = v * v;
#pragma unroll
    for (int off = 32; off > 0; off >>= 1) {
      s1 += __shfl_down(s1, off);
      s2 += __shfl_down(s2, off);
    }
    s1 = __shfl(s1, 0);
    s2 = __shfl(s2, 0);
    const float mu = s1 * (1.0f / 64.0f);
    const float var = s2 * (1.0f / 64.0f) - mu * mu;
    float y = (v - mu) * rsqrtf(var + LN_EPS) * g2[tid] + b2[tid];
    y += ident[(size_t)n * 64 + tid];
    out[(size_t)n * 64 + tid] = y > 0.f ? y : expm1f(y);
  }
}

extern "C" void kernel_launch(void* const* d_in, const int* in_sizes, int n_in,
                              void* d_out, int out_size, void* d_ws, size_t ws_size,
                              hipStream_t stream) {
  const float* x        = (const float*)d_in[0];
  const int*   ei       = (const int*)d_in[1];
  const float* W1       = (const float*)d_in[2];
  const float* att_src1 = (const float*)d_in[3];
  const float* att_dst1 = (const float*)d_in[4];
  const float* bias1    = (const float*)d_in[5];
  const float* g1       = (const float*)d_in[6];
  const float* b1       = (const float*)d_in[7];
  const float* W2       = (const float*)d_in[8];
  const float* att_src2 = (const float*)d_in[9];
  const float* att_dst2 = (const float*)d_in[10];
  const float* bias2    = (const float*)d_in[11];
  const float* g2       = (const float*)d_in[12];
  const float* b2       = (const float*)d_in[13];
  const float* Wres     = (const float*)d_in[14];
  const float* bres     = (const float*)d_in[15];

  const int N = in_sizes[0] / 128;   // 50000
  const int E = in_sizes[1] / 2;     // 800000
  const int IN = 128;
  const int Etot = E + N;

  const int* srcs = ei;
  const int* dsts = ei + E;

  // workspace layout
  char* p = (char*)d_ws;
  float* ident = (float*)p;            p += (size_t)N * 64 * 4;
  float* as_   = (float*)p;            p += (size_t)N * HH * 4;
  float* ad_   = (float*)p;            p += (size_t)N * HH * 4;
  int* rowptr  = (int*)p;              p += (size_t)(N + 4) * 4;
  int* deg     = (int*)p;              p += (size_t)N * 4;
  int* bsum    = (int*)p;              p += 256 * 4;
  int* col     = (int*)p;              p += (size_t)Etot * 4;
  p = (char*)(((uintptr_t)p + 15) & ~(uintptr_t)15);
  unsigned short* xb    = (unsigned short*)p; p += (size_t)N * IN * 2;
  unsigned short* hlinb = (unsigned short*)p; p += (size_t)N * HC * 2;
  unsigned short* h1b   = (unsigned short*)p; p += (size_t)N * HC * 2;
  unsigned short* wt1   = (unsigned short*)p; p += (size_t)IN * HC * 2;
  unsigned short* wt2   = (unsigned short*)p; p += (size_t)HC * HC * 2;
  unsigned short* wtres = (unsigned short*)p; p += (size_t)IN * 64 * 2;

  const int m64 = (N + 63) / 64;
  const int m128 = (N + 127) / 128;
  const int nscan = (N + 255) / 256;
  dim3 blk(256);

  // ---- dtype prep ----
  cvt_bf16_x4<<<(N * IN / 4 + 255) / 256, blk, 0, stream>>>(x, xb, N * IN / 4);
  cvt_weights<<<(106496 + 255) / 256, blk, 0, stream>>>(W1, W2, Wres, wt1, wt2, wtres);

  // ---- CSR build ----
  (void)hipMemsetAsync(deg, 0, (size_t)N * sizeof(int), stream);
  deg_hist<<<(E + 255) / 256, blk, 0, stream>>>(dsts, deg, E);
  scan_block<<<nscan, blk, 0, stream>>>(deg, rowptr, bsum, N);
  scan_top<<<1, blk, 0, stream>>>(bsum, nscan);
  scan_add<<<nscan, blk, 0, stream>>>(bsum, rowptr, deg, N);
  csr_scatter<<<(Etot + 255) / 256, blk, 0, stream>>>(srcs, dsts, deg, col, E, N);

  // residual projection (fp32 out)
  gemm_bf16<float><<<dim3(m64, 1), blk, 0, stream>>>(xb, wtres, bres, ident, N, 64, IN);

  // ---- GAT layer 1 ----
  gemm128<<<dim3(m128, 2), blk, 0, stream>>>(
      xb, wt1, hlinb, att_src1, att_dst1, as_, ad_, N, HC, IN);
  csr_agg_ln1<<<N, blk, 0, stream>>>(rowptr, col, as_, ad_, hlinb, bias1, g1, b1, h1b);

  // ---- GAT layer 2 ----
  gemm128<<<dim3(m128, 2), blk, 0, stream>>>(
      h1b, wt2, hlinb, att_src2, att_dst2, as_, ad_, N, HC, HC);
  csr_agg_final<<<N, blk, 0, stream>>>(rowptr, col, as_, ad_, hlinb, ident,
                                       bias2, g2, b2, (float*)d_out);
}

// Round 11
// 473.335 us; speedup vs baseline: 1.5059x; 1.0151x over previous
//
#include <hip/hip_runtime.h>
#include <math.h>

// Problem constants: N=50000, IN=128, H=4, C=64, HC=256
#define HH 4
#define CC 64
#define HC 256

static constexpr float NEG_SLOPE = 0.2f;
static constexpr float LN_EPS = 1e-5f;

typedef __attribute__((ext_vector_type(8))) short short8;
typedef __attribute__((ext_vector_type(4))) float floatx4;
typedef __attribute__((ext_vector_type(4))) unsigned int uintx4;

__device__ __forceinline__ float bf2f(unsigned short u) {
  return __uint_as_float(((unsigned int)u) << 16);
}
__device__ __forceinline__ unsigned short f2bf(float f) {
  unsigned int u = __float_as_uint(f);
  u = (u + 0x7fff + ((u >> 16) & 1)) >> 16;  // round-to-nearest-even
  return (unsigned short)u;
}

// 8 bf16 (as uintx4) * w -> acc[8]; 2 VALU per element
__device__ __forceinline__ void macc8(float* acc, uintx4 h, float w) {
  acc[0] += w * __uint_as_float(h.x << 16);
  acc[1] += w * __uint_as_float(h.x & 0xffff0000u);
  acc[2] += w * __uint_as_float(h.y << 16);
  acc[3] += w * __uint_as_float(h.y & 0xffff0000u);
  acc[4] += w * __uint_as_float(h.z << 16);
  acc[5] += w * __uint_as_float(h.z & 0xffff0000u);
  acc[6] += w * __uint_as_float(h.w << 16);
  acc[7] += w * __uint_as_float(h.w & 0xffff0000u);
}

// A-operand load: 8 contiguous elements starting at idx -> short8 (bf16)
__device__ __forceinline__ short8 ldA8(const unsigned short* A, size_t idx) {
  return *(const short8*)(A + idx);
}
__device__ __forceinline__ short8 ldA8(const float* A, size_t idx) {
  const float4 u = *(const float4*)(A + idx);
  const float4 v = *(const float4*)(A + idx + 4);
  short8 r;
  r[0] = (short)f2bf(u.x); r[1] = (short)f2bf(u.y);
  r[2] = (short)f2bf(u.z); r[3] = (short)f2bf(u.w);
  r[4] = (short)f2bf(v.x); r[5] = (short)f2bf(v.y);
  r[6] = (short)f2bf(v.z); r[7] = (short)f2bf(v.w);
  return r;
}

// ---------------- prep: weight transposes (combined) + deg zero ----------------
// wt1c [384,128]: rows 0..255 = W1^T, 256..319 = Wres^T, 320..383 = 0
// wt2  [256,256] = W2^T
__global__ __launch_bounds__(256) void prep_kernel(
    const float* __restrict__ W1, const float* __restrict__ W2,
    const float* __restrict__ Wres,
    unsigned short* __restrict__ wt1c, unsigned short* __restrict__ wt2,
    int* __restrict__ deg, int N) {
  const int idx = blockIdx.x * 256 + threadIdx.x;
  if (idx < 49152) {                       // wt1c: r=idx>>7, k=idx&127
    const int r = idx >> 7, k = idx & 127;
    float v = 0.f;
    if (r < 256) v = W1[k * 256 + r];
    else if (r < 320) v = Wres[k * 64 + (r - 256)];
    wt1c[idx] = f2bf(v);
  } else if (idx < 49152 + 65536) {        // wt2
    const int i = idx - 49152;
    const int r = i >> 8, k = i & 255;
    wt2[i] = f2bf(W2[k * 256 + r]);
  } else if (idx < 49152 + 65536 + N) {
    deg[idx - 49152 - 65536] = 0;
  }
}

// ---------------- 128x128-tile bf16 MFMA GEMM, fused alpha + residual tile ----------------
// A [M,K] (fp32 or bf16); BT [*,K] bf16. 4 waves in 2x2 quadrants.
// col0 < 256 : head tiles -> C bf16 [M,256] + in-register alpha reduce.
// col0 == 256: residual tile -> ident fp32 [M,64] + bres (ch==0 waves only).
template <typename AT>
__global__ __launch_bounds__(256) void gemm128(
    const AT* __restrict__ A, const unsigned short* __restrict__ BT,
    unsigned short* __restrict__ C,
    float* __restrict__ ident, const float* __restrict__ bres,
    const float* __restrict__ att_src, const float* __restrict__ att_dst,
    float* __restrict__ as_, float* __restrict__ ad_,
    int M, int K) {
  __shared__ unsigned short As[128][40];
  __shared__ unsigned short Bs[128][40];
  const int tid = threadIdx.x;
  const int w = tid >> 6, lane = tid & 63;
  const int q = lane >> 4, mr = lane & 15;
  const int rh = w >> 1, ch = w & 1;          // quadrant (row-half, col-half)
  const int row0 = blockIdx.x * 128;
  const int col0 = blockIdx.y * 128;
  const int sr = tid >> 2;                    // 0..63 staging row
  const int sk = (tid & 3) * 8;               // k offset (elements)

  floatx4 acc[4][4] = {};

  short8 a0 = {}, a1 = {}, b0, b1;
  {
    const int r0 = row0 + sr, r1 = row0 + sr + 64;
    if (r0 < M) a0 = ldA8(A, (size_t)r0 * K + sk);
    if (r1 < M) a1 = ldA8(A, (size_t)r1 * K + sk);
    b0 = *(const short8*)(BT + (size_t)(col0 + sr) * K + sk);
    b1 = *(const short8*)(BT + (size_t)(col0 + sr + 64) * K + sk);
  }
  for (int k0 = 0; k0 < K; k0 += 32) {
    *(short8*)(&As[sr][sk]) = a0;
    *(short8*)(&As[sr + 64][sk]) = a1;
    *(short8*)(&Bs[sr][sk]) = b0;
    *(short8*)(&Bs[sr + 64][sk]) = b1;
    __syncthreads();
    const int kn = k0 + 32;
    if (kn < K) {
      const int r0 = row0 + sr, r1 = row0 + sr + 64;
      a0 = (r0 < M) ? ldA8(A, (size_t)r0 * K + kn + sk) : short8{};
      a1 = (r1 < M) ? ldA8(A, (size_t)r1 * K + kn + sk) : short8{};
      b0 = *(const short8*)(BT + (size_t)(col0 + sr) * K + kn + sk);
      b1 = *(const short8*)(BT + (size_t)(col0 + sr + 64) * K + kn + sk);
    }
    short8 af[4], bf[4];
#pragma unroll
    for (int i = 0; i < 4; ++i)
      af[i] = *(const short8*)(&As[rh * 64 + i * 16 + mr][q * 8]);
#pragma unroll
    for (int j = 0; j < 4; ++j)
      bf[j] = *(const short8*)(&Bs[ch * 64 + j * 16 + mr][q * 8]);
#pragma unroll
    for (int i = 0; i < 4; ++i)
#pragma unroll
      for (int j = 0; j < 4; ++j)
        acc[i][j] = __builtin_amdgcn_mfma_f32_16x16x32_bf16(af[i], bf[j], acc[i][j], 0, 0, 0);
    __syncthreads();
  }
  if (col0 < 256) {
    // head tiles: bf16 store. C/D layout: col=mr, row=q*4+rr per 16x16 tile.
#pragma unroll
    for (int i = 0; i < 4; ++i)
#pragma unroll
      for (int j = 0; j < 4; ++j)
#pragma unroll
        for (int rr = 0; rr < 4; ++rr) {
          const int row = row0 + rh * 64 + i * 16 + q * 4 + rr;
          if (row < M) {
            const int cc = col0 + ch * 64 + j * 16 + mr;
            C[(size_t)row * HC + cc] = f2bf(acc[i][j][rr]);
          }
        }
    // fused alpha: this wave's 64-col quadrant = one head
    const int hh = (col0 >> 6) + ch;
    float pa[16] = {}, pb[16] = {};
#pragma unroll
    for (int j = 0; j < 4; ++j) {
      const float a_s = att_src[hh * 64 + j * 16 + mr];
      const float a_d = att_dst[hh * 64 + j * 16 + mr];
#pragma unroll
      for (int i = 0; i < 4; ++i)
#pragma unroll
        for (int rr = 0; rr < 4; ++rr) {
          pa[i * 4 + rr] += acc[i][j][rr] * a_s;
          pb[i * 4 + rr] += acc[i][j][rr] * a_d;
        }
    }
#pragma unroll
    for (int off = 1; off < 16; off <<= 1) {
#pragma unroll
      for (int t = 0; t < 16; ++t) {
        pa[t] += __shfl_xor(pa[t], off);
        pb[t] += __shfl_xor(pb[t], off);
      }
    }
    if (mr == 0) {
#pragma unroll
      for (int i = 0; i < 4; ++i)
#pragma unroll
        for (int rr = 0; rr < 4; ++rr) {
          const int row = row0 + rh * 64 + i * 16 + q * 4 + rr;
          if (row < M) {
            as_[row * 4 + hh] = pa[i * 4 + rr];
            ad_[row * 4 + hh] = pb[i * 4 + rr];
          }
        }
    }
  } else if (ch == 0) {
    // residual tile: cols 256..319 -> ident[M,64] fp32 + bres
#pragma unroll
    for (int i = 0; i < 4; ++i)
#pragma unroll
      for (int j = 0; j < 4; ++j)
#pragma unroll
        for (int rr = 0; rr < 4; ++rr) {
          const int row = row0 + rh * 64 + i * 16 + q * 4 + rr;
          if (row < M) {
            const int cc = j * 16 + mr;
            ident[(size_t)row * 64 + cc] = acc[i][j][rr] + bres[cc];
          }
        }
  }
}

// ================= CSR construction =================
__global__ __launch_bounds__(256) void deg_hist(
    const int* __restrict__ dsts, int* __restrict__ deg, int E) {
  const int e = blockIdx.x * 256 + threadIdx.x;
  if (e < E) atomicAdd(&deg[dsts[e]], 1);
}

// deg counts edges only; +1 here for the self-loop.
__global__ __launch_bounds__(256) void scan_block(
    const int* __restrict__ deg, int* __restrict__ rowptr, int* __restrict__ bsum, int N) {
  const int b = blockIdx.x, t = threadIdx.x, g = b * 256 + t;
  const int lane = t & 63, w = t >> 6;
  int x = (g < N) ? deg[g] + 1 : 0;
#pragma unroll
  for (int off = 1; off < 64; off <<= 1) {
    const int y = __shfl_up(x, off);
    if (lane >= off) x += y;
  }
  __shared__ int wsum[4];
  if (lane == 63) wsum[w] = x;
  __syncthreads();
  int add = 0;
  for (int i = 0; i < w; ++i) add += wsum[i];
  x += add;
  if (g < N) rowptr[g + 1] = x;
  if (t == 255) bsum[b] = x;
}

__global__ __launch_bounds__(256) void scan_top(int* __restrict__ bsum, int nb) {
  const int t = threadIdx.x;
  const int lane = t & 63, w = t >> 6;
  const int v = (t < nb) ? bsum[t] : 0;
  int x = v;
#pragma unroll
  for (int off = 1; off < 64; off <<= 1) {
    const int y = __shfl_up(x, off);
    if (lane >= off) x += y;
  }
  __shared__ int wsum[4];
  if (lane == 63) wsum[w] = x;
  __syncthreads();
  int add = 0;
  for (int i = 0; i < w; ++i) add += wsum[i];
  x += add;
  if (t < nb) bsum[t] = x - v;  // exclusive
}

__global__ __launch_bounds__(256) void scan_add(
    const int* __restrict__ bsum, int* __restrict__ rowptr,
    int* __restrict__ deg_to_cursor, int N) {
  const int g = blockIdx.x * 256 + threadIdx.x;
  if (g == 0) rowptr[0] = 0;
  if (g < N) {
    const int v = rowptr[g + 1] + bsum[blockIdx.x];
    rowptr[g + 1] = v;
    deg_to_cursor[g] = v - deg_to_cursor[g] - 1;  // exclusive start
  }
}

__global__ __launch_bounds__(256) void csr_scatter(
    const int* __restrict__ srcs, const int* __restrict__ dsts,
    int* __restrict__ cursor, int* __restrict__ col, int E, int N) {
  const int e = blockIdx.x * 256 + threadIdx.x;
  if (e >= E + N) return;
  int s, d;
  if (e < E) { s = srcs[e]; d = dsts[e]; }
  else       { s = e - E; d = s; }
  const int pos = atomicAdd(&cursor[d], 1);
  col[pos] = s;
}

// ================= fused CSR aggregation (bf16, vectorized + 2x unrolled) =================
__global__ __launch_bounds__(256) void csr_agg_ln1(
    const int* __restrict__ rowptr, const int* __restrict__ col,
    const float* __restrict__ as_, const float* __restrict__ ad_,
    const unsigned short* __restrict__ hlin, const float* __restrict__ bias1,
    const float* __restrict__ g1, const float* __restrict__ b1,
    unsigned short* __restrict__ h1) {
  const int n = blockIdx.x;
  const int tid = threadIdx.x;
  const int hh = tid >> 6, lane = tid & 63;
  const int sub = lane >> 3, cg = lane & 7;
  const uintx4* hb = (const uintx4*)(hlin + hh * 64 + cg * 8);  // row stride 32 uintx4
  const float adv = ad_[n * 4 + hh];
  const int beg = rowptr[n], end = rowptr[n + 1];
  float acc[8] = {};
  float wsum = 0.f;
  for (int off = beg; off < end; off += 64) {
    const int len = min(64, end - off);
    int s_l = 0;
    float w_l = 0.f;
    if (lane < len) {
      s_l = col[off + lane];
      float v = as_[s_l * 4 + hh] + adv;
      v = v > 0.f ? v : NEG_SLOPE * v;
      w_l = expf(v);
    }
    wsum += w_l;
    int j = 0;
    for (; j + 16 <= len; j += 16) {
      const int sA = __shfl(s_l, j + sub);
      const int sB = __shfl(s_l, j + 8 + sub);
      const float wA = __shfl(w_l, j + sub);
      const float wB = __shfl(w_l, j + 8 + sub);
      const uintx4 hA = hb[(size_t)sA * 32];
      const uintx4 hB = hb[(size_t)sB * 32];
      macc8(acc, hA, wA);
      macc8(acc, hB, wB);
    }
    for (; j < len; j += 8) {
      const int s = __shfl(s_l, j + sub);
      const float w = __shfl(w_l, j + sub);
      macc8(acc, hb[(size_t)s * 32], w);
    }
  }
#pragma unroll
  for (int off = 32; off > 0; off >>= 1) wsum += __shfl_xor(wsum, off);
#pragma unroll
  for (int t = 0; t < 8; ++t) {
    acc[t] += __shfl_xor(acc[t], 8);
    acc[t] += __shfl_xor(acc[t], 16);
    acc[t] += __shfl_xor(acc[t], 32);
  }
  __shared__ float vals[HC];
  if (sub == 0) {
    const float inv = 1.0f / wsum;
#pragma unroll
    for (int t = 0; t < 8; ++t) vals[hh * 64 + cg * 8 + t] = acc[t] * inv;
  }
  __syncthreads();
  const float val = vals[tid] + bias1[tid];
  float s1 = val, s2 = val * val;
#pragma unroll
  for (int off = 32; off > 0; off >>= 1) {
    s1 += __shfl_down(s1, off);
    s2 += __shfl_down(s2, off);
  }
  __shared__ float ws1[4], ws2[4];
  if (lane == 0) { ws1[hh] = s1; ws2[hh] = s2; }
  __syncthreads();
  const float tot1 = ws1[0] + ws1[1] + ws1[2] + ws1[3];
  const float tot2 = ws2[0] + ws2[1] + ws2[2] + ws2[3];
  const float mu = tot1 * (1.0f / HC);
  const float var = tot2 * (1.0f / HC) - mu * mu;
  float y = (val - mu) * rsqrtf(var + LN_EPS) * g1[tid] + b1[tid];
  y = y > 0.f ? y : expm1f(y);
  h1[(size_t)n * HC + tid] = f2bf(y);
}

__global__ __launch_bounds__(256) void csr_agg_final(
    const int* __restrict__ rowptr, const int* __restrict__ col,
    const float* __restrict__ as_, const float* __restrict__ ad_,
    const unsigned short* __restrict__ hlin, const float* __restrict__ ident,
    const float* __restrict__ bias2, const float* __restrict__ g2,
    const float* __restrict__ b2, float* __restrict__ out) {
  const int n = blockIdx.x;
  const int tid = threadIdx.x;
  const int hh = tid >> 6, lane = tid & 63;
  const int sub = lane >> 3, cg = lane & 7;
  const uintx4* hb = (const uintx4*)(hlin + hh * 64 + cg * 8);
  const float adv = ad_[n * 4 + hh];
  const int beg = rowptr[n], end = rowptr[n + 1];
  float acc[8] = {};
  float wsum = 0.f;
  for (int off = beg; off < end; off += 64) {
    const int len = min(64, end - off);
    int s_l = 0;
    float w_l = 0.f;
    if (lane < len) {
      s_l = col[off + lane];
      float v = as_[s_l * 4 + hh] + adv;
      v = v > 0.f ? v : NEG_SLOPE * v;
      w_l = expf(v);
    }
    wsum += w_l;
    int j = 0;
    for (; j + 16 <= len; j += 16) {
      const int sA = __shfl(s_l, j + sub);
      const int sB = __shfl(s_l, j + 8 + sub);
      const float wA = __shfl(w_l, j + sub);
      const float wB = __shfl(w_l, j + 8 + sub);
      const uintx4 hA = hb[(size_t)sA * 32];
      const uintx4 hB = hb[(size_t)sB * 32];
      macc8(acc, hA, wA);
      macc8(acc, hB, wB);
    }
    for (; j < len; j += 8) {
      const int s = __shfl(s_l, j + sub);
      const float w = __shfl(w_l, j + sub);
      macc8(acc, hb[(size_t)s * 32], w);
    }
  }
#pragma unroll
  for (int off = 32; off > 0; off >>= 1) wsum += __shfl_xor(wsum, off);
#pragma unroll
  for (int t = 0; t < 8; ++t) {
    acc[t] += __shfl_xor(acc[t], 8);
    acc[t] += __shfl_xor(acc[t], 16);
    acc[t] += __shfl_xor(acc[t], 32);
  }
  __shared__ float sm[4][64];
  if (sub == 0) {
    const float inv = 1.0f / wsum;
#pragma unroll
    for (int t = 0; t < 8; ++t) sm[hh][cg * 8 + t] = acc[t] * inv;
  }
  __syncthreads();
  if (tid < 64) {
    float v = 0.25f * (sm[0][tid] + sm[1][tid] + sm[2][tid] + sm[3][tid]) + bias2[tid];
    float s1 = v, s2 = v * v;
#pragma unroll
    for (int off = 32; off > 0; off >>= 1) {
      s1 += __shfl_down(s1, off);
      s2 += __shfl_down(s2, off);
    }
    s1 = __shfl(s1, 0);
    s2 = __shfl(s2, 0);
    const float mu = s1 * (1.0f / 64.0f);
    const float var = s2 * (1.0f / 64.0f) - mu * mu;
    float y = (v - mu) * rsqrtf(var + LN_EPS) * g2[tid] + b2[tid];
    y += ident[(size_t)n * 64 + tid];
    out[(size_t)n * 64 + tid] = y > 0.f ? y : expm1f(y);
  }
}

extern "C" void kernel_launch(void* const* d_in, const int* in_sizes, int n_in,
                              void* d_out, int out_size, void* d_ws, size_t ws_size,
                              hipStream_t stream) {
  const float* x        = (const float*)d_in[0];
  const int*   ei       = (const int*)d_in[1];
  const float* W1       = (const float*)d_in[2];
  const float* att_src1 = (const float*)d_in[3];
  const float* att_dst1 = (const float*)d_in[4];
  const float* bias1    = (const float*)d_in[5];
  const float* g1       = (const float*)d_in[6];
  const float* b1       = (const float*)d_in[7];
  const float* W2       = (const float*)d_in[8];
  const float* att_src2 = (const float*)d_in[9];
  const float* att_dst2 = (const float*)d_in[10];
  const float* bias2    = (const float*)d_in[11];
  const float* g2       = (const float*)d_in[12];
  const float* b2       = (const float*)d_in[13];
  const float* Wres     = (const float*)d_in[14];
  const float* bres     = (const float*)d_in[15];

  const int N = in_sizes[0] / 128;   // 50000
  const int E = in_sizes[1] / 2;     // 800000
  const int IN = 128;
  const int Etot = E + N;

  const int* srcs = ei;
  const int* dsts = ei + E;

  // workspace layout
  char* p = (char*)d_ws;
  float* ident = (float*)p;            p += (size_t)N * 64 * 4;
  float* as_   = (float*)p;            p += (size_t)N * HH * 4;
  float* ad_   = (float*)p;            p += (size_t)N * HH * 4;
  int* rowptr  = (int*)p;              p += (size_t)(N + 4) * 4;
  int* deg     = (int*)p;              p += (size_t)N * 4;
  int* bsum    = (int*)p;              p += 256 * 4;
  int* col     = (int*)p;              p += (size_t)Etot * 4;
  p = (char*)(((uintptr_t)p + 15) & ~(uintptr_t)15);
  unsigned short* hlinb = (unsigned short*)p; p += (size_t)N * HC * 2;
  unsigned short* h1b   = (unsigned short*)p; p += (size_t)N * HC * 2;
  unsigned short* wt1c  = (unsigned short*)p; p += (size_t)384 * IN * 2;
  unsigned short* wt2   = (unsigned short*)p; p += (size_t)HC * HC * 2;

  const int m128 = (N + 127) / 128;
  const int nscan = (N + 255) / 256;
  const int prep_items = 49152 + 65536 + N;
  dim3 blk(256);

  // ---- prep: weight transposes + deg zero (one kernel) ----
  prep_kernel<<<(prep_items + 255) / 256, blk, 0, stream>>>(
      W1, W2, Wres, wt1c, wt2, deg, N);

  // ---- CSR build ----
  deg_hist<<<(E + 255) / 256, blk, 0, stream>>>(dsts, deg, E);
  scan_block<<<nscan, blk, 0, stream>>>(deg, rowptr, bsum, N);
  scan_top<<<1, blk, 0, stream>>>(bsum, nscan);
  scan_add<<<nscan, blk, 0, stream>>>(bsum, rowptr, deg, N);
  csr_scatter<<<(Etot + 255) / 256, blk, 0, stream>>>(srcs, dsts, deg, col, E, N);

  // ---- GAT layer 1 (+ fused residual projection, fp32 A) ----
  gemm128<float><<<dim3(m128, 3), blk, 0, stream>>>(
      x, wt1c, hlinb, ident, bres, att_src1, att_dst1, as_, ad_, N, IN);
  csr_agg_ln1<<<N, blk, 0, stream>>>(rowptr, col, as_, ad_, hlinb, bias1, g1, b1, h1b);

  // ---- GAT layer 2 (bf16 A) ----
  gemm128<unsigned short><<<dim3(m128, 2), blk, 0, stream>>>(
      h1b, wt2, hlinb, nullptr, nullptr, att_src2, att_dst2, as_, ad_, N, HC);
  csr_agg_final<<<N, blk, 0, stream>>>(rowptr, col, as_, ad_, hlinb, ident,
                                       bias2, g2, b2, (float*)d_out);
}